// Round 4
// baseline (79.422 us; speedup 1.0000x reference)
//
#include <hip/hip_runtime.h>

#define C2  2.8853900817779268f   // 2*log2(e)
#define L2E 1.4426950408889634f   // log2(e)

// ---------------- Projection (outputs PRE-SCALED by C2 = 2*log2e):
__global__ __launch_bounds__(256) void proj_kernel(
    const float* __restrict__ inputs, const float* __restrict__ memory,
    const float* __restrict__ W_in, const float* __restrict__ b_in,
    const float* __restrict__ W_mem,
    float* __restrict__ in_item, float* __restrict__ mem_item)
{
  const int NIN = 2048;
  int r0 = blockIdx.x * 16;
  int tid = threadIdx.x;
  __shared__ float4 wlds[64][64];   // [k4][d], swizzled

  const float* Wsel; const float* Abase; float* O; int ar0; bool has_bias = (r0 < NIN);
  if (has_bias) { Wsel = W_in;  Abase = inputs; O = in_item;  ar0 = r0; }
  else          { Wsel = W_mem; Abase = memory; O = mem_item; ar0 = r0 - NIN; }

  const float4* Wv = reinterpret_cast<const float4*>(Wsel);
  #pragma unroll
  for (int u = 0; u < 16; ++u) {
    int e = tid + u * 256;
    int k4 = e & 63, dd = e >> 6;
    wlds[k4][dd ^ (k4 & 7)] = Wv[e];
  }
  int d = tid & 63, rg = tid >> 6;
  float bias = has_bias ? b_in[d] : 0.f;
  __syncthreads();

  const float4* A0 = reinterpret_cast<const float4*>(Abase + (size_t)(ar0 + rg) * 256);
  float acc0 = 0.f, acc1 = 0.f, acc2 = 0.f, acc3 = 0.f;
  #pragma unroll 8
  for (int k4 = 0; k4 < 64; ++k4) {
    float4 w  = wlds[k4][d ^ (k4 & 7)];
    float4 a0 = A0[k4];
    float4 a1 = A0[k4 + 256];
    float4 a2 = A0[k4 + 512];
    float4 a3 = A0[k4 + 768];
    acc0 += a0.x*w.x + a0.y*w.y + a0.z*w.z + a0.w*w.w;
    acc1 += a1.x*w.x + a1.y*w.y + a1.z*w.z + a1.w*w.w;
    acc2 += a2.x*w.x + a2.y*w.y + a2.z*w.z + a2.w*w.w;
    acc3 += a3.x*w.x + a3.y*w.y + a3.z*w.z + a3.w*w.w;
  }
  O[(size_t)(ar0 + rg     ) * 64 + d] = (acc0 + bias) * C2;
  O[(size_t)(ar0 + rg +  4) * 64 + d] = (acc1 + bias) * C2;
  O[(size_t)(ar0 + rg +  8) * 64 + d] = (acc2 + bias) * C2;
  O[(size_t)(ar0 + rg + 12) * 64 + d] = (acc3 + bias) * C2;
}

// ---------------- Fused score+softmax+PV over a SLICE of Tm (blockIdx.z).
// Writes UNNORMALIZED partial output + partial psum to workspace.
__global__ __launch_bounds__(512, 4) void attn_kernel(
    const float* __restrict__ in_item,   // (B,Ti,64), pre-scaled
    const float* __restrict__ mem_item,  // (B,Tm,64), pre-scaled
    const float* __restrict__ memory,    // (B,Tm,256)
    const int* __restrict__ in_len, const int* __restrict__ mem_len,
    const float* __restrict__ W_final,   // (64)
    float* __restrict__ o_part,          // (nsplit, B*Ti, 256)
    float* __restrict__ psum_part,       // (nsplit, B*Ti)
    int m_count)                         // Tm / nsplit
{
  const int Ti = 512, Tm = 1024, DM = 256;
  const int TI = 4, MT = 128;
  const int NT = m_count >> 7;
  int b = blockIdx.y;
  int i0 = blockIdx.x * TI;
  int z = blockIdx.z;
  int m_begin = z * m_count;
  int tid = threadIdx.x;

  __shared__ float4 smem[16 * 128];  // 32KB: mt4[d4][128]; epilogue: osl[8][4][64]
  __shared__ float4 pt4[128];
  __shared__ float  red[8];

  const int s_ii = __builtin_amdgcn_readfirstlane(tid >> 7);  // wave-uniform row index
  const int s_ml = tid & 127;
  const int dq = tid & 63, wv_ = tid >> 6;

  float4 qreg[16];
  {
    const float4* qrow = reinterpret_cast<const float4*>(
        in_item + ((size_t)b * Ti + i0 + s_ii) * 64);
    #pragma unroll
    for (int j = 0; j < 16; ++j) qreg[j] = qrow[j];
  }

  float Wsum = 0.f;
  #pragma unroll
  for (int j = 0; j < 64; ++j) Wsum += W_final[j];   // uniform -> s_loads
  const float c1 = L2E * Wsum;
  const float4* Wf4 = reinterpret_cast<const float4*>(W_final);

  int ilen = in_len[b], mlen = mem_len[b];
  const bool row_valid = (i0 + s_ii) < ilen;

  const float4* mem4 = reinterpret_cast<const float4*>(mem_item);
  const float* memb = memory + (size_t)b * Tm * DM;

  float psum = 0.f;
  float4 a0 = make_float4(0,0,0,0), a1 = a0, a2 = a0, a3 = a0;

  // stage tile 0
  #pragma unroll
  for (int u = 0; u < 4; ++u) {
    int e = tid + u * 512, dd4 = e & 15, mm = e >> 4;
    smem[dd4 * 128 + (mm ^ (dd4 & 7))] = mem4[((size_t)b * Tm + m_begin + mm) * 16 + dd4];
  }
  __syncthreads();

  #pragma unroll 1
  for (int t = 0; t < NT; ++t) {
    int m0 = m_begin + t * MT;

    // ---- score ----
    float4 S4 = make_float4(0,0,0,0);
    #pragma unroll
    for (int d4 = 0; d4 < 16; ++d4) {
      float4 mv = smem[d4 * 128 + (s_ml ^ (d4 & 7))];
      float4 qv = qreg[d4];
      float4 w  = Wf4[d4];
      S4.x = fmaf(w.x, __builtin_amdgcn_rcpf(1.0f + __builtin_amdgcn_exp2f(qv.x + mv.x)), S4.x);
      S4.y = fmaf(w.y, __builtin_amdgcn_rcpf(1.0f + __builtin_amdgcn_exp2f(qv.y + mv.y)), S4.y);
      S4.z = fmaf(w.z, __builtin_amdgcn_rcpf(1.0f + __builtin_amdgcn_exp2f(qv.z + mv.z)), S4.z);
      S4.w = fmaf(w.w, __builtin_amdgcn_rcpf(1.0f + __builtin_amdgcn_exp2f(qv.w + mv.w)), S4.w);
    }
    float S = (S4.x + S4.y) + (S4.z + S4.w);
    int m = m0 + s_ml;
    float p = row_valid ? ((m < mlen) ? __builtin_amdgcn_exp2f(fmaf(-C2, S, c1)) : 0.f)
                        : 1.0f;
    reinterpret_cast<float*>(&pt4[s_ml])[s_ii] = p;
    psum += p;
    __syncthreads();   // pt4 ready; all smem(t) reads done

    // ---- stage next tile (overlaps PV) ----
    if (t + 1 < NT) {
      int m0n = m0 + MT;
      #pragma unroll
      for (int u = 0; u < 4; ++u) {
        int e = tid + u * 512, dd4 = e & 15, mm = e >> 4;
        smem[dd4 * 128 + (mm ^ (dd4 & 7))] = mem4[((size_t)b * Tm + m0n + mm) * 16 + dd4];
      }
    }

    // ---- PV ----
    {
      const float* mpb = memb + (size_t)(m0 + wv_ * 16) * DM + dq * 4;
      #pragma unroll
      for (int mm = 0; mm < 16; ++mm) {
        float4 v = *reinterpret_cast<const float4*>(mpb + (size_t)mm * DM);
        float4 pp = pt4[wv_ * 16 + mm];
        a0.x += pp.x*v.x; a0.y += pp.x*v.y; a0.z += pp.x*v.z; a0.w += pp.x*v.w;
        a1.x += pp.y*v.x; a1.y += pp.y*v.y; a1.z += pp.y*v.z; a1.w += pp.y*v.w;
        a2.x += pp.z*v.x; a2.y += pp.z*v.y; a2.z += pp.z*v.z; a2.w += pp.z*v.w;
        a3.x += pp.w*v.x; a3.y += pp.w*v.y; a3.z += pp.w*v.z; a3.w += pp.w*v.w;
      }
    }
    __syncthreads();   // smem(t+1) staged; pt4 consumers done
  }

  // ---- epilogue: write unnormalized partials ----
  {
    float s = psum;
    #pragma unroll
    for (int o = 32; o >= 1; o >>= 1) s += __shfl_xor(s, o);
    if (dq == 0) red[wv_] = s;
  }
  smem[(wv_ * 4 + 0) * 64 + dq] = a0;
  smem[(wv_ * 4 + 1) * 64 + dq] = a1;
  smem[(wv_ * 4 + 2) * 64 + dq] = a2;
  smem[(wv_ * 4 + 3) * 64 + dq] = a3;
  __syncthreads();

  if (tid < 256) {
    int ii = tid >> 6, d2 = tid & 63;
    float4 s = smem[ii * 64 + d2];
    #pragma unroll
    for (int w = 1; w < 8; ++w) {
      float4 v = smem[(w * 4 + ii) * 64 + d2];
      s.x += v.x; s.y += v.y; s.z += v.z; s.w += v.w;
    }
    size_t r = (size_t)b * Ti + i0 + ii;
    reinterpret_cast<float4*>(o_part)[((size_t)z * 2048 + r) * 64 + d2] = s;
  }
  if (tid < TI) {
    psum_part[(size_t)z * 2048 + (size_t)b * Ti + i0 + tid] = red[2 * tid] + red[2 * tid + 1];
  }
}

// ---------------- Combine: out = sum_z o_part / sum_z psum
__global__ __launch_bounds__(256) void combine_kernel(
    const float* __restrict__ o_part, const float* __restrict__ psum_part,
    float* __restrict__ out, int nsplit)
{
  int e = blockIdx.x * 256 + threadIdx.x;   // float4 index, 0..131071
  int r = e >> 6;
  const float4* op4 = reinterpret_cast<const float4*>(o_part);
  float4 o = op4[e];
  float s = psum_part[r];
  if (nsplit == 2) {
    float4 o1 = op4[e + 131072];
    o.x += o1.x; o.y += o1.y; o.z += o1.z; o.w += o1.w;
    s += psum_part[r + 2048];
  }
  float inv = __builtin_amdgcn_rcpf(s);
  o.x *= inv; o.y *= inv; o.z *= inv; o.w *= inv;
  reinterpret_cast<float4*>(out)[e] = o;
}

extern "C" void kernel_launch(void* const* d_in, const int* in_sizes, int n_in,
                              void* d_out, int out_size, void* d_ws, size_t ws_size,
                              hipStream_t stream) {
  const float* inputs   = (const float*)d_in[0];  // (4,512,256)
  const float* memory   = (const float*)d_in[1];  // (4,1024,256)
  const int*   in_len   = (const int*)  d_in[2];  // (4)
  const int*   mem_len  = (const int*)  d_in[3];  // (4)
  const float* W_in     = (const float*)d_in[4];  // (64,256)
  const float* b_in     = (const float*)d_in[5];  // (64)
  const float* W_mem    = (const float*)d_in[6];  // (64,256)
  const float* W_final  = (const float*)d_in[7];  // (64)
  float* out = (float*)d_out;                     // (4,512,256)

  float* in_item   = (float*)d_ws;                  // 512 KB  (131072 f)
  float* mem_item  = in_item + 2048 * 64;           // 1 MB    (262144 f)
  float* o_part    = mem_item + 4096 * 64;          // up to 4 MB (2*524288 f)
  float* psum_part = o_part + 2 * 2048 * 256;       // 16 KB

  size_t need2 = (size_t)(131072 + 262144 + 2 * 524288 + 2 * 2048 + 64) * 4;
  int nsplit = (ws_size >= need2) ? 2 : 1;

  proj_kernel<<<384, 256, 0, stream>>>(inputs, memory, W_in, b_in, W_mem,
                                       in_item, mem_item);
  attn_kernel<<<dim3(128, 4, nsplit), 512, 0, stream>>>(
      in_item, mem_item, memory, in_len, mem_len, W_final,
      o_part, psum_part, 1024 / nsplit);
  combine_kernel<<<512, 256, 0, stream>>>(o_part, psum_part, out, nsplit);
}